// Round 2
// baseline (717.184 us; speedup 1.0000x reference)
//
#include <hip/hip_runtime.h>
#include <hip/hip_bf16.h>

typedef unsigned short u16;
typedef unsigned int u32;
typedef __attribute__((ext_vector_type(8))) short short8;
typedef __attribute__((ext_vector_type(4))) float f4;
typedef __attribute__((ext_vector_type(4))) u32 u4;
typedef __attribute__((ext_vector_type(2))) u32 u2;

#define MFMA(a, b, c) __builtin_amdgcn_mfma_f32_16x16x32_bf16((a), (b), (c), 0, 0, 0)

// ---- constants ----
#define TT 256
#define BB 1024
#define NN (TT * BB)          // 262144 rows
// ws layout in u16 units:
#define WS_HID3 0             // N*128 bf16 frag-order (hid3, later reused as hs)
#define WS_WF   (NN * 128)    // 33554432
#define OFF_W1  0
#define OFF_W2  16384
#define OFF_W3  20480
#define OFF_WIH 24576
#define OFF_WHH 90112
#define OFF_WA  155648
#define WF_TOT  159744
#define WS_XG   (WS_WF + WF_TOT)
#define XG_U16  ((size_t)NN * 512)
// total u16 with xg: 33554432 + 159744 + 134217728 = 167931904 -> 335863808 bytes
#define WS_NEED_BIG 335863808ULL

static __device__ __forceinline__ u16 f2bf(float f) {
    u32 u = __float_as_uint(f);
    u32 r = (u + 0x7FFFu + ((u >> 16) & 1u)) >> 16;
    return (u16)r;
}
static __device__ __forceinline__ short8 pack8(f4 a, f4 b) {
    short8 r;
    r[0] = (short)f2bf(a[0]); r[1] = (short)f2bf(a[1]);
    r[2] = (short)f2bf(a[2]); r[3] = (short)f2bf(a[3]);
    r[4] = (short)f2bf(b[0]); r[5] = (short)f2bf(b[1]);
    r[6] = (short)f2bf(b[2]); r[7] = (short)f2bf(b[3]);
    return r;
}
static __device__ __forceinline__ short8 u4_to_s8(u4 v) {
    union { u4 u; short8 s; } t; t.u = v; return t.s;
}
static __device__ __forceinline__ float sigf(float x) {
    return __builtin_amdgcn_rcpf(1.f + __builtin_amdgcn_exp2f(-1.442695040888963f * x));
}
static __device__ __forceinline__ float tanhf_fast(float x) {
    return 2.f * __builtin_amdgcn_rcpf(1.f + __builtin_amdgcn_exp2f(-2.885390081777927f * x)) - 1.f;
}
// LDS-only barrier: no vmcnt drain, so global stores/prefetches stay in flight.
static __device__ __forceinline__ void lds_barrier() {
    asm volatile("s_waitcnt lgkmcnt(0)\n\ts_barrier" ::: "memory");
}

// ---------------- K0: convert weights fp32 -> bf16 fragment order ----------------
static __device__ void convW128(const float* src, int Nn, u16* dst, int tid, int nth) {
    int tot = Nn * 128;
    for (int d = tid; d < tot; d += nth) {
        int j = d & 7, l = (d >> 3) & 63, ck = d >> 9;
        int kc = ck & 3, nt = ck >> 2;
        int n = nt * 16 + (l & 15), k = kc * 32 + ((l >> 4) << 3) + j;
        dst[d] = f2bf(src[n * 128 + k]);
    }
}
static __device__ void convW32(const float* src, int Nn, u16* dst, int tid, int nth) {
    int tot = Nn * 32;
    for (int d = tid; d < tot; d += nth) {
        int j = d & 7, l = (d >> 3) & 63, nt = d >> 9;
        int n = nt * 16 + (l & 15), k = ((l >> 4) << 3) + j;
        dst[d] = f2bf(src[n * 32 + k]);
    }
}

__global__ void k0_conv(const float* __restrict__ W1, const float* __restrict__ W2,
                        const float* __restrict__ W3, const float* __restrict__ Wih,
                        const float* __restrict__ Whh, const float* __restrict__ Wa,
                        const float* __restrict__ Wc, u16* __restrict__ wf) {
    int tid = blockIdx.x * blockDim.x + threadIdx.x;
    int nth = gridDim.x * blockDim.x;
    convW128(W1, 128, wf + OFF_W1, tid, nth);
    convW128(W2, 32, wf + OFF_W2, tid, nth);
    convW32(W3, 128, wf + OFF_W3, tid, nth);
    convW128(Wih, 512, wf + OFF_WIH, tid, nth);
    convW128(Whh, 512, wf + OFF_WHH, tid, nth);
    for (int d = tid; d < 32 * 128; d += nth) {
        int j = d & 7, l = (d >> 3) & 63, ck = d >> 9;
        int kc = ck & 3, nt = ck >> 2;
        int n = nt * 16 + (l & 15), k = kc * 32 + ((l >> 4) << 3) + j;
        float v = (n < 18) ? Wa[n * 128 + k] : ((n == 18) ? Wc[k] : 0.f);
        wf[OFF_WA + d] = f2bf(v);
    }
}

// ---------------- K1: encoder (3 layers) -> hid3 bf16 frag-order ----------------
// LDS scratch is per-wave: NO barriers needed. 4096 blocks x 4 waves = 16384 chunks.
__global__ __launch_bounds__(256) void k1_enc(
    const float* __restrict__ x, const float* __restrict__ b1, const float* __restrict__ b2,
    const float* __restrict__ b3, const u16* __restrict__ wf, u16* __restrict__ hid3f) {
    __shared__ __align__(16) u16 scr[4][2560];

    int tid = threadIdx.x, wv = tid >> 6, lane = tid & 63;
    int m = lane & 15, q = lane >> 4;
    u16* s1 = scr[wv];
    u16* s2 = scr[wv] + 2048;
    const short8* W1v = (const short8*)(wf + OFF_W1);
    const short8* W2v = (const short8*)(wf + OFF_W2);
    const short8* W3v = (const short8*)(wf + OFF_W3);
    int c = blockIdx.x * 4 + wv;  // chunk id [0,16384)

    short8 a1[4];
    const float* xr = x + (size_t)(c * 16 + m) * 128 + q * 8;
#pragma unroll
    for (int kc = 0; kc < 4; ++kc) {
        f4 f0 = *(const f4*)(xr + kc * 32);
        f4 f1 = *(const f4*)(xr + kc * 32 + 4);
        a1[kc] = pack8(f0, f1);
    }
    // Layer 1: 128 -> 128
#pragma unroll
    for (int nt = 0; nt < 8; ++nt) {
        f4 acc = {0.f, 0.f, 0.f, 0.f};
#pragma unroll
        for (int kc = 0; kc < 4; ++kc) acc = MFMA(a1[kc], W1v[(nt * 4 + kc) * 64 + lane], acc);
        int col = nt * 16 + m;
        float bb = b1[col];
        int base = (col >> 5) * 512 + ((col >> 3) & 3) * 128 + (col & 7);
#pragma unroll
        for (int p = 0; p < 4; ++p) {
            float v = acc[p] + bb; v = v > 0.f ? v : 0.f;
            s1[base + (q * 4 + p) * 8] = f2bf(v);
        }
    }
    short8 a2[4];
#pragma unroll
    for (int kc = 0; kc < 4; ++kc) a2[kc] = *(const short8*)(s1 + kc * 512 + lane * 8);
    // Layer 2: 128 -> 32
#pragma unroll
    for (int nt = 0; nt < 2; ++nt) {
        f4 acc = {0.f, 0.f, 0.f, 0.f};
#pragma unroll
        for (int kc = 0; kc < 4; ++kc) acc = MFMA(a2[kc], W2v[(nt * 4 + kc) * 64 + lane], acc);
        int col = nt * 16 + m;
        float bb = b2[col];
        int base = (col >> 3) * 128 + (col & 7);
#pragma unroll
        for (int p = 0; p < 4; ++p) {
            float v = acc[p] + bb; v = v > 0.f ? v : 0.f;
            s2[base + (q * 4 + p) * 8] = f2bf(v);
        }
    }
    short8 a3 = *(const short8*)(s2 + lane * 8);
    // Layer 3: 32 -> 128
#pragma unroll
    for (int nt = 0; nt < 8; ++nt) {
        f4 acc = {0.f, 0.f, 0.f, 0.f};
        acc = MFMA(a3, W3v[nt * 64 + lane], acc);
        int col = nt * 16 + m;
        float bb = b3[col];
        int base = (col >> 5) * 512 + ((col >> 3) & 3) * 128 + (col & 7);
#pragma unroll
        for (int p = 0; p < 4; ++p) {
            float v = acc[p] + bb; v = v > 0.f ? v : 0.f;
            s1[base + (q * 4 + p) * 8] = f2bf(v);
        }
    }
    u4* dst = (u4*)hid3f + (size_t)c * 256;
#pragma unroll
    for (int kc = 0; kc < 4; ++kc) dst[kc * 64 + lane] = *(const u4*)(s1 + kc * 512 + lane * 8);
}

// ---------------- K2: xg = hid3 @ Wih^T + bih + bhh, bf16, K3-ready layout ----------------
// layout: xg[((chunk*32 + nt)*64 + lane)*4 + k], nt = g*8 + wv, k = row 4q+k, col m.
__global__ __launch_bounds__(512) void k2_xg(
    const u16* __restrict__ hid3f, const u16* __restrict__ wf,
    const float* __restrict__ bih, const float* __restrict__ bhh, u16* __restrict__ xg) {
    int tid = threadIdx.x, wv = tid >> 6, lane = tid & 63;
    int m = lane & 15;
    const short8* WIv = (const short8*)(wf + OFF_WIH);
    short8 wb[4][4];
    float bias[4];
#pragma unroll
    for (int j = 0; j < 4; ++j) {
        int nt = wv * 4 + j;
#pragma unroll
        for (int kc = 0; kc < 4; ++kc) wb[j][kc] = WIv[(nt * 4 + kc) * 64 + lane];
        bias[j] = bih[nt * 16 + m] + bhh[nt * 16 + m];
    }
    const u4* A = (const u4*)hid3f;
    for (int i = 0; i < 64; ++i) {
        size_t c = (size_t)blockIdx.x * 64 + i;
        u4 av[4];
#pragma unroll
        for (int kc = 0; kc < 4; ++kc) av[kc] = A[(c * 4 + kc) * 64 + lane];
#pragma unroll
        for (int j = 0; j < 4; ++j) {
            f4 acc = {0.f, 0.f, 0.f, 0.f};
#pragma unroll
            for (int kc = 0; kc < 4; ++kc) acc = MFMA(u4_to_s8(av[kc]), wb[j][kc], acc);
            int nt = wv * 4 + j;
            u2 pk;
            float v0 = acc[0] + bias[j], v1 = acc[1] + bias[j];
            float v2 = acc[2] + bias[j], v3 = acc[3] + bias[j];
            pk[0] = ((u32)f2bf(v1) << 16) | (u32)f2bf(v0);
            pk[1] = ((u32)f2bf(v3) << 16) | (u32)f2bf(v2);
            *(u2*)(xg + ((c * 32 + (size_t)nt) * 64 + lane) * 4) = pk;
        }
    }
}

// ---------------- K3: LSTM scan, h-GEMM only (xg precomputed) ----------------
__global__ __launch_bounds__(512) void k3_scan(
    const u16* __restrict__ xg, u16* __restrict__ hsout, const u16* __restrict__ wf,
    const float* __restrict__ done, const float* __restrict__ h0, const float* __restrict__ c0) {
    __shared__ __align__(16) u16 hbuf[2][2048];
    __shared__ __align__(16) float dls[4096];

    int tid = threadIdx.x, wv = tid >> 6, lane = tid & 63;
    int m = lane & 15, q = lane >> 4;
    int u = wv * 16 + m;
    int rb = blockIdx.x * 16;
    const short8* WHv = (const short8*)(wf + OFF_WHH);

    short8 wh[4][4];
#pragma unroll
    for (int g = 0; g < 4; ++g)
#pragma unroll
        for (int kc = 0; kc < 4; ++kc)
            wh[g][kc] = WHv[(((g * 8 + wv) * 4) + kc) * 64 + lane];

    for (int i = tid; i < 4096; i += 512) {
        int t = i >> 4, r = i & 15;
        dls[i] = 1.0f - done[(size_t)t * BB + rb + r];
    }
    float cst[4];
#pragma unroll
    for (int k = 0; k < 4; ++k) {
        int r = 4 * q + k;
        cst[k] = c0[(size_t)(rb + r) * 128 + u];
        float hv = h0[(size_t)(rb + r) * 128 + u];
        hbuf[0][(u >> 5) * 512 + (((u >> 3) & 3) * 16 + r) * 8 + (u & 7)] = f2bf(hv);
    }
    const u2* XG = (const u2*)xg;  // u2 index = (chunk*32 + nt)*64 + lane
    u2 xbuf[2][4];
#pragma unroll
    for (int g = 0; g < 4; ++g) {
        xbuf[0][g] = XG[((size_t)(0 * 64 + blockIdx.x) * 32 + g * 8 + wv) * 64 + lane];
        xbuf[1][g] = XG[((size_t)(1 * 64 + blockIdx.x) * 32 + g * 8 + wv) * 64 + lane];
    }
    __syncthreads();

    for (int t = 0; t < TT; ++t) {
        const u16* hc = hbuf[t & 1];
        u16* hn = hbuf[(t + 1) & 1];
        short8 ah[4];
#pragma unroll
        for (int kc = 0; kc < 4; ++kc) ah[kc] = *(const short8*)(hc + kc * 512 + lane * 8);
        f4 aH[4];
#pragma unroll
        for (int g = 0; g < 4; ++g) aH[g] = (f4){0.f, 0.f, 0.f, 0.f};
#pragma unroll
        for (int kc = 0; kc < 4; ++kc)
#pragma unroll
            for (int g = 0; g < 4; ++g) aH[g] = MFMA(ah[kc], wh[g][kc], aH[g]);

        u2 xcur[4];
#pragma unroll
        for (int g = 0; g < 4; ++g) xcur[g] = xbuf[t & 1][g];
        // prefetch distance 2 (crosses two LDS-only barriers; no vmcnt drain)
        int tp = (t + 2 < TT) ? (t + 2) : (TT - 1);
#pragma unroll
        for (int g = 0; g < 4; ++g)
            xbuf[t & 1][g] = XG[((size_t)(tp * 64 + blockIdx.x) * 32 + g * 8 + wv) * 64 + lane];

        f4 dm = *(const f4*)(dls + t * 16 + 4 * q);
#pragma unroll
        for (int k = 0; k < 4; ++k) {
            float mm = dm[k];
            float pre[4];
#pragma unroll
            for (int g = 0; g < 4; ++g) {
                u32 w = (k < 2) ? xcur[g][0] : xcur[g][1];
                u32 bits = (k & 1) ? (w & 0xFFFF0000u) : (w << 16);
                pre[g] = __uint_as_float(bits) + mm * aH[g][k];
            }
            float ii = sigf(pre[0]), ff = sigf(pre[1]);
            float gg = tanhf_fast(pre[2]), oo = sigf(pre[3]);
            float cc = ff * (mm * cst[k]) + ii * gg;
            cst[k] = cc;
            float hh = oo * tanhf_fast(cc);
            hn[(u >> 5) * 512 + (((u >> 3) & 3) * 16 + (4 * q + k)) * 8 + (u & 7)] = f2bf(hh);
        }
        lds_barrier();
        if (wv < 4) {
            u4 v = *(const u4*)(hn + wv * 512 + lane * 8);
            ((u4*)hsout)[(((size_t)t * 64 + blockIdx.x) * 4 + wv) * 64 + lane] = v;
        }
    }
}

// ---------------- K3-fallback: round-1 fused scan (used if ws too small for xg) ----------------
__global__ __launch_bounds__(512) void k3_lstm(
    u16* __restrict__ hws, const u16* __restrict__ wf, const float* __restrict__ bih,
    const float* __restrict__ bhh, const float* __restrict__ done,
    const float* __restrict__ h0, const float* __restrict__ c0) {
    __shared__ __align__(16) u16 hbuf[2][2048];
    __shared__ __align__(16) float dls[4096];

    int tid = threadIdx.x, wv = tid >> 6, lane = tid & 63;
    int u15 = lane & 15, q = lane >> 4;
    int u = wv * 16 + u15;
    int rb = blockIdx.x * 16;
    const short8* WHv = (const short8*)(wf + OFF_WHH);
    const short8* WIv = (const short8*)(wf + OFF_WIH);

    short8 wh[4][4], wi[4][4];
#pragma unroll
    for (int g = 0; g < 4; ++g)
#pragma unroll
        for (int kc = 0; kc < 4; ++kc) {
            int nt = g * 8 + wv;
            wh[g][kc] = WHv[(nt * 4 + kc) * 64 + lane];
            wi[g][kc] = WIv[(nt * 4 + kc) * 64 + lane];
        }
    float bg[4];
#pragma unroll
    for (int g = 0; g < 4; ++g) bg[g] = bih[g * 128 + u] + bhh[g * 128 + u];

    for (int i = tid; i < 4096; i += 512) {
        int t = i >> 4, r = i & 15;
        dls[i] = 1.0f - done[(size_t)t * BB + rb + r];
    }
    float cst[4];
#pragma unroll
    for (int k = 0; k < 4; ++k) {
        int r = 4 * q + k;
        cst[k] = c0[(size_t)(rb + r) * 128 + u];
        float hv = h0[(size_t)(rb + r) * 128 + u];
        hbuf[0][(u >> 5) * 512 + (((u >> 3) & 3) * 16 + r) * 8 + (u & 7)] = f2bf(hv);
    }
    const u4* h3 = (const u4*)hws;
    u4 xf[4];
#pragma unroll
    for (int kc = 0; kc < 4; ++kc) xf[kc] = h3[((size_t)blockIdx.x * 4 + kc) * 64 + lane];
    __syncthreads();

    for (int t = 0; t < TT; ++t) {
        const u16* hc = hbuf[t & 1];
        u16* hn = hbuf[(t + 1) & 1];
        short8 ah[4];
#pragma unroll
        for (int kc = 0; kc < 4; ++kc) ah[kc] = *(const short8*)(hc + kc * 512 + lane * 8);
        f4 aH[4], aX[4];
#pragma unroll
        for (int g = 0; g < 4; ++g) { aH[g] = (f4){0.f, 0.f, 0.f, 0.f}; aX[g] = (f4){0.f, 0.f, 0.f, 0.f}; }
#pragma unroll
        for (int kc = 0; kc < 4; ++kc) {
            short8 xs = u4_to_s8(xf[kc]);
#pragma unroll
            for (int g = 0; g < 4; ++g) {
                aH[g] = MFMA(ah[kc], wh[g][kc], aH[g]);
                aX[g] = MFMA(xs, wi[g][kc], aX[g]);
            }
        }
        if (t < TT - 1) {
#pragma unroll
            for (int kc = 0; kc < 4; ++kc)
                xf[kc] = h3[(((size_t)(t + 1) * 64 + blockIdx.x) * 4 + kc) * 64 + lane];
        }
        f4 dm = *(const f4*)(dls + t * 16 + 4 * q);
#pragma unroll
        for (int k = 0; k < 4; ++k) {
            float mm = dm[k];
            float ip = aX[0][k] + bg[0] + mm * aH[0][k];
            float fp = aX[1][k] + bg[1] + mm * aH[1][k];
            float gp = aX[2][k] + bg[2] + mm * aH[2][k];
            float op = aX[3][k] + bg[3] + mm * aH[3][k];
            float ii = sigf(ip), ff = sigf(fp), gg = tanhf_fast(gp), oo = sigf(op);
            float cc = ff * (mm * cst[k]) + ii * gg;
            cst[k] = cc;
            float hh = oo * tanhf_fast(cc);
            hn[(u >> 5) * 512 + (((u >> 3) & 3) * 16 + (4 * q + k)) * 8 + (u & 7)] = f2bf(hh);
        }
        lds_barrier();
        if (wv < 4) {
            u4 v = *(const u4*)(hn + wv * 512 + lane * 8);
            ((u4*)hws)[(((size_t)t * 64 + blockIdx.x) * 4 + wv) * 64 + lane] = v;
        }
    }
}

// ---------------- K4: heads (logits + value) ----------------
__global__ __launch_bounds__(256) void k4_heads(
    const u16* __restrict__ hsf, const u16* __restrict__ wf,
    const float* __restrict__ ba, const float* __restrict__ bc, float* __restrict__ out) {
    int tid = threadIdx.x, wv = tid >> 6, lane = tid & 63;
    int m = lane & 15, q = lane >> 4;
    int wid = blockIdx.x * 4 + wv;
    const short8* WAv = (const short8*)(wf + OFF_WA);
    short8 wab[2][4];
#pragma unroll
    for (int nt = 0; nt < 2; ++nt)
#pragma unroll
        for (int kc = 0; kc < 4; ++kc) wab[nt][kc] = WAv[(nt * 4 + kc) * 64 + lane];
    const short8* A = (const short8*)hsf;
    for (int it = 0; it < 8; ++it) {
        int c = wid + it * 2048;
        short8 a[4];
#pragma unroll
        for (int kc = 0; kc < 4; ++kc) a[kc] = A[((size_t)c * 4 + kc) * 64 + lane];
#pragma unroll
        for (int nt = 0; nt < 2; ++nt) {
            f4 acc = {0.f, 0.f, 0.f, 0.f};
#pragma unroll
            for (int kc = 0; kc < 4; ++kc) acc = MFMA(a[kc], wab[nt][kc], acc);
            int col = nt * 16 + m;
            if (col < 19) {
                float bb = (col < 18) ? ba[col] : bc[0];
#pragma unroll
                for (int p = 0; p < 4; ++p)
                    out[(size_t)(c * 16 + q * 4 + p) * 19 + col] = acc[p] + bb;
            }
        }
    }
}

extern "C" void kernel_launch(void* const* d_in, const int* in_sizes, int n_in,
                              void* d_out, int out_size, void* d_ws, size_t ws_size,
                              hipStream_t stream) {
    const float* x    = (const float*)d_in[0];
    const float* done = (const float*)d_in[1];
    const float* h0   = (const float*)d_in[2];
    const float* c0   = (const float*)d_in[3];
    const float* W1   = (const float*)d_in[4];
    const float* b1   = (const float*)d_in[5];
    const float* W2   = (const float*)d_in[6];
    const float* b2   = (const float*)d_in[7];
    const float* W3   = (const float*)d_in[8];
    const float* b3   = (const float*)d_in[9];
    const float* Wih  = (const float*)d_in[10];
    const float* Whh  = (const float*)d_in[11];
    const float* bih  = (const float*)d_in[12];
    const float* bhh  = (const float*)d_in[13];
    const float* Wa   = (const float*)d_in[14];
    const float* ba   = (const float*)d_in[15];
    const float* Wc   = (const float*)d_in[16];
    const float* bc   = (const float*)d_in[17];
    float* out = (float*)d_out;

    u16* ws = (u16*)d_ws;
    u16* hid3f = ws + WS_HID3;
    u16* wf    = ws + WS_WF;
    u16* xg    = ws + WS_XG;

    hipLaunchKernelGGL(k0_conv, dim3(128), dim3(256), 0, stream,
                       W1, W2, W3, Wih, Whh, Wa, Wc, wf);
    hipLaunchKernelGGL(k1_enc, dim3(4096), dim3(256), 0, stream,
                       x, b1, b2, b3, wf, hid3f);
    if (ws_size >= WS_NEED_BIG) {
        hipLaunchKernelGGL(k2_xg, dim3(256), dim3(512), 0, stream,
                           hid3f, wf, bih, bhh, xg);
        hipLaunchKernelGGL(k3_scan, dim3(64), dim3(512), 0, stream,
                           xg, hid3f, wf, done, h0, c0);
    } else {
        hipLaunchKernelGGL(k3_lstm, dim3(64), dim3(512), 0, stream,
                           hid3f, wf, bih, bhh, done, h0, c0);
    }
    hipLaunchKernelGGL(k4_heads, dim3(512), dim3(256), 0, stream,
                       hid3f, wf, ba, bc, out);
}

// Round 3
// 598.757 us; speedup vs baseline: 1.1978x; 1.1978x over previous
//
#include <hip/hip_runtime.h>
#include <hip/hip_bf16.h>

typedef unsigned short u16;
typedef unsigned int u32;
typedef __attribute__((ext_vector_type(8))) short short8;
typedef __attribute__((ext_vector_type(4))) float f4;
typedef __attribute__((ext_vector_type(4))) u32 u4;
typedef __attribute__((ext_vector_type(2))) u32 u2;

#define MFMA(a, b, c) __builtin_amdgcn_mfma_f32_16x16x32_bf16((a), (b), (c), 0, 0, 0)

// ---- constants ----
#define TT 256
#define BB 1024
#define NN (TT * BB)          // 262144 rows
#define SC1 1.4426950408889634f   // log2(e), folded into i,f,o gate rows
#define SC2 2.8853900817779268f   // 2*log2(e), folded into g gate rows

// wf internal offsets (u16 units)
#define OFF_W1  0
#define OFF_W2  16384
#define OFF_W3  20480
#define OFF_WIH 24576
#define OFF_WHH 90112
#define OFF_WA  155648
#define WF_TOT  159744

// big-path ws layout (u16 units): xg[NN*128 u2 = 134217728 u16] | hs[33554432] | wf[159744]
#define WS_HS_OFF 134217728
#define WS_WF_OFF 167772160
#define WS_NEED_BIG 335863808ULL
// fallback layout: hid3f[33554432] | wf[159744]

static __device__ __forceinline__ u16 f2bf(float f) {
    u32 u = __float_as_uint(f);
    u32 r = (u + 0x7FFFu + ((u >> 16) & 1u)) >> 16;
    return (u16)r;
}
static __device__ __forceinline__ short8 pack8(f4 a, f4 b) {
    short8 r;
    r[0] = (short)f2bf(a[0]); r[1] = (short)f2bf(a[1]);
    r[2] = (short)f2bf(a[2]); r[3] = (short)f2bf(a[3]);
    r[4] = (short)f2bf(b[0]); r[5] = (short)f2bf(b[1]);
    r[6] = (short)f2bf(b[2]); r[7] = (short)f2bf(b[3]);
    return r;
}
static __device__ __forceinline__ short8 u4_to_s8(u4 v) {
    union { u4 u; short8 s; } t; t.u = v; return t.s;
}
// x already scaled by log2e (folded into weights/bias)
static __device__ __forceinline__ float sig2(float x) {
    return __builtin_amdgcn_rcpf(1.f + __builtin_amdgcn_exp2f(-x));
}
// x already scaled by 2*log2e
static __device__ __forceinline__ float tanh2pre(float x) {
    return 2.f * __builtin_amdgcn_rcpf(1.f + __builtin_amdgcn_exp2f(-x)) - 1.f;
}
// unscaled argument (cell state)
static __device__ __forceinline__ float tanh_c(float x) {
    return 2.f * __builtin_amdgcn_rcpf(1.f + __builtin_amdgcn_exp2f(-SC2 * x)) - 1.f;
}
// LDS-only barrier: no vmcnt drain; global stores / prefetch loads stay in flight.
static __device__ __forceinline__ void lds_barrier() {
    asm volatile("s_waitcnt lgkmcnt(0)\n\ts_barrier" ::: "memory");
}

// ---------------- K0: weights fp32 -> bf16 fragment order (gate rows pre-scaled) ----------------
static __device__ void convW128(const float* src, int Nn, u16* dst, int tid, int nth) {
    int tot = Nn * 128;
    for (int d = tid; d < tot; d += nth) {
        int j = d & 7, l = (d >> 3) & 63, ck = d >> 9;
        int kc = ck & 3, nt = ck >> 2;
        int n = nt * 16 + (l & 15), k = kc * 32 + ((l >> 4) << 3) + j;
        dst[d] = f2bf(src[n * 128 + k]);
    }
}
static __device__ void convW128s(const float* src, u16* dst, int tid, int nth) {
    // 512 x 128, rows scaled per gate: i,f,o -> SC1 ; g -> SC2
    int tot = 512 * 128;
    for (int d = tid; d < tot; d += nth) {
        int j = d & 7, l = (d >> 3) & 63, ck = d >> 9;
        int kc = ck & 3, nt = ck >> 2;
        int n = nt * 16 + (l & 15), k = kc * 32 + ((l >> 4) << 3) + j;
        float s = ((n >> 7) == 2) ? SC2 : SC1;
        dst[d] = f2bf(src[n * 128 + k] * s);
    }
}
static __device__ void convW32(const float* src, int Nn, u16* dst, int tid, int nth) {
    int tot = Nn * 32;
    for (int d = tid; d < tot; d += nth) {
        int j = d & 7, l = (d >> 3) & 63, nt = d >> 9;
        int n = nt * 16 + (l & 15), k = ((l >> 4) << 3) + j;
        dst[d] = f2bf(src[n * 32 + k]);
    }
}

__global__ void k0_conv(const float* __restrict__ W1, const float* __restrict__ W2,
                        const float* __restrict__ W3, const float* __restrict__ Wih,
                        const float* __restrict__ Whh, const float* __restrict__ Wa,
                        const float* __restrict__ Wc, u16* __restrict__ wf) {
    int tid = blockIdx.x * blockDim.x + threadIdx.x;
    int nth = gridDim.x * blockDim.x;
    convW128(W1, 128, wf + OFF_W1, tid, nth);
    convW128(W2, 32, wf + OFF_W2, tid, nth);
    convW32(W3, 128, wf + OFF_W3, tid, nth);
    convW128s(Wih, wf + OFF_WIH, tid, nth);
    convW128s(Whh, wf + OFF_WHH, tid, nth);
    for (int d = tid; d < 32 * 128; d += nth) {
        int j = d & 7, l = (d >> 3) & 63, ck = d >> 9;
        int kc = ck & 3, nt = ck >> 2;
        int n = nt * 16 + (l & 15), k = kc * 32 + ((l >> 4) << 3) + j;
        float v = (n < 18) ? Wa[n * 128 + k] : ((n == 18) ? Wc[k] : 0.f);
        wf[OFF_WA + d] = f2bf(v);
    }
}

// ---------------- K1-fused: encoder (3 layers) + xg = hid3 @ Wih^T + bias ----------------
// xg layout: u2[R*128 + u] holding 4 packed bf16 gate pre-acts (i,f,g,o) for (row R, unit u).
__global__ __launch_bounds__(256) void k1_fused(
    const float* __restrict__ x, const float* __restrict__ b1, const float* __restrict__ b2,
    const float* __restrict__ b3, const float* __restrict__ bih, const float* __restrict__ bhh,
    const u16* __restrict__ wf, u2* __restrict__ xg) {
    __shared__ __align__(16) u16 scr[4][2560];
    __shared__ float biasL[512];

    int tid = threadIdx.x, wv = tid >> 6, lane = tid & 63;
    int m = lane & 15, q = lane >> 4;
    u16* s1 = scr[wv];
    u16* s2 = scr[wv] + 2048;
    const short8* W1v = (const short8*)(wf + OFF_W1);
    const short8* W2v = (const short8*)(wf + OFF_W2);
    const short8* W3v = (const short8*)(wf + OFF_W3);
    const short8* WIv = (const short8*)(wf + OFF_WIH);
    int c = blockIdx.x * 4 + wv;  // chunk id [0,16384)

    for (int i = tid; i < 512; i += 256)
        biasL[i] = (bih[i] + bhh[i]) * (((i >> 7) == 2) ? SC2 : SC1);

    short8 a1[4];
    const float* xr = x + (size_t)(c * 16 + m) * 128 + q * 8;
#pragma unroll
    for (int kc = 0; kc < 4; ++kc) {
        f4 f0 = *(const f4*)(xr + kc * 32);
        f4 f1 = *(const f4*)(xr + kc * 32 + 4);
        a1[kc] = pack8(f0, f1);
    }
    // Layer 1: 128 -> 128
#pragma unroll
    for (int nt = 0; nt < 8; ++nt) {
        f4 acc = {0.f, 0.f, 0.f, 0.f};
#pragma unroll
        for (int kc = 0; kc < 4; ++kc) acc = MFMA(a1[kc], W1v[(nt * 4 + kc) * 64 + lane], acc);
        int col = nt * 16 + m;
        float bb = b1[col];
        int base = (col >> 5) * 512 + ((col >> 3) & 3) * 128 + (col & 7);
#pragma unroll
        for (int p = 0; p < 4; ++p) {
            float v = acc[p] + bb; v = v > 0.f ? v : 0.f;
            s1[base + (q * 4 + p) * 8] = f2bf(v);
        }
    }
    short8 a2[4];
#pragma unroll
    for (int kc = 0; kc < 4; ++kc) a2[kc] = *(const short8*)(s1 + kc * 512 + lane * 8);
    // Layer 2: 128 -> 32
#pragma unroll
    for (int nt = 0; nt < 2; ++nt) {
        f4 acc = {0.f, 0.f, 0.f, 0.f};
#pragma unroll
        for (int kc = 0; kc < 4; ++kc) acc = MFMA(a2[kc], W2v[(nt * 4 + kc) * 64 + lane], acc);
        int col = nt * 16 + m;
        float bb = b2[col];
        int base = (col >> 3) * 128 + (col & 7);
#pragma unroll
        for (int p = 0; p < 4; ++p) {
            float v = acc[p] + bb; v = v > 0.f ? v : 0.f;
            s2[base + (q * 4 + p) * 8] = f2bf(v);
        }
    }
    short8 a3 = *(const short8*)(s2 + lane * 8);
    // Layer 3: 32 -> 128 (hid3 stays in s1, frag order)
#pragma unroll
    for (int nt = 0; nt < 8; ++nt) {
        f4 acc = {0.f, 0.f, 0.f, 0.f};
        acc = MFMA(a3, W3v[nt * 64 + lane], acc);
        int col = nt * 16 + m;
        float bb = b3[col];
        int base = (col >> 5) * 512 + ((col >> 3) & 3) * 128 + (col & 7);
#pragma unroll
        for (int p = 0; p < 4; ++p) {
            float v = acc[p] + bb; v = v > 0.f ? v : 0.f;
            s1[base + (q * 4 + p) * 8] = f2bf(v);
        }
    }
    __syncthreads();  // biasL visibility (once; also s1 complete for this wave)

    // xg part: gates^T = Wih @ hid3^T. A = Wih-frag (M=gate units), B = hid3-frag from s1.
    short8 bfr[4];
#pragma unroll
    for (int kc = 0; kc < 4; ++kc) bfr[kc] = *(const short8*)(s1 + kc * 512 + lane * 8);
    size_t R = (size_t)c * 16 + m;  // this lane's batch row (C col)
#pragma unroll
    for (int uw = 0; uw < 8; ++uw) {
        f4 acc[4];
#pragma unroll
        for (int g = 0; g < 4; ++g) acc[g] = (f4){0.f, 0.f, 0.f, 0.f};
#pragma unroll
        for (int kc = 0; kc < 4; ++kc) {
#pragma unroll
            for (int g = 0; g < 4; ++g) {
                int nt = g * 8 + uw;
                acc[g] = MFMA(WIv[(nt * 4 + kc) * 64 + lane], bfr[kc], acc[g]);
            }
        }
        // pack p=0..3 (units uw*16+4q+p), 4 gates each -> 2 dwordx4 stores
        u4 st0, st1;
#pragma unroll
        for (int p = 0; p < 4; ++p) {
            int u = uw * 16 + 4 * q + p;
            u32 lo = ((u32)f2bf(acc[1][p] + biasL[128 + u]) << 16) |
                     (u32)f2bf(acc[0][p] + biasL[u]);
            u32 hi = ((u32)f2bf(acc[3][p] + biasL[384 + u]) << 16) |
                     (u32)f2bf(acc[2][p] + biasL[256 + u]);
            if (p < 2) { st0[2 * p] = lo; st0[2 * p + 1] = hi; }
            else       { st1[2 * (p - 2)] = lo; st1[2 * (p - 2) + 1] = hi; }
        }
        u4* dst = (u4*)(xg + R * 128 + uw * 16 + 4 * q);
        dst[0] = st0;
        dst[1] = st1;
    }
}

// ---------------- K3: LSTM scan, 256 blocks x 4 rows x 512 threads ----------------
// gates^T MFMA (A=Whh regs, B=h-frag LDS); h-part pre-acts redistributed via LDS so all
// 512 threads do exactly 1 cell each; xg read per-cell (u2) with distance-2 reg prefetch.
__global__ __launch_bounds__(512) void k3_scan(
    const u2* __restrict__ xg, u16* __restrict__ hs, const u16* __restrict__ wf,
    const float* __restrict__ done, const float* __restrict__ h0, const float* __restrict__ c0) {
    __shared__ __align__(16) u16 hbuf[2][16 * 136];  // rows 0-3 live, 4-15 zero; pad 136
    __shared__ __align__(16) float pre[4 * 516];     // [row][unit*4+gate], row stride 516
    __shared__ float dls[1024];                      // (1-done)[t*4+r]

    int tid = threadIdx.x, wv = tid >> 6, lane = tid & 63;
    int m = lane & 15, q = lane >> 4;
    int rb = blockIdx.x * 4;
    const short8* WHv = (const short8*)(wf + OFF_WHH);

    short8 wh[4][4];  // A-frags: gate g, unit-group wv
#pragma unroll
    for (int g = 0; g < 4; ++g)
#pragma unroll
        for (int kc = 0; kc < 4; ++kc)
            wh[g][kc] = WHv[(((g * 8 + wv) * 4) + kc) * 64 + lane];

    // zero hbuf rows 4..15 of both buffers
    for (int i = tid; i < 2 * 12 * 136; i += 512) {
        int b = i / 1632, rem = i % 1632;
        hbuf[b][(4 + rem / 136) * 136 + (rem % 136)] = 0;
    }
    for (int i = tid; i < 1024; i += 512)
        dls[i] = 1.0f - done[(size_t)(i >> 2) * BB + rb + (i & 3)];

    int r = tid >> 7, u = tid & 127;     // this thread's cell
    float cst = c0[(size_t)(rb + r) * 128 + u];
    hbuf[0][r * 136 + u] = f2bf(h0[(size_t)(rb + r) * 128 + u]);

    u2 xp0 = xg[(size_t)blockIdx.x * 512 + tid];                 // t=0
    u2 xp1 = xg[(size_t)131072 + (size_t)blockIdx.x * 512 + tid];// t=1
    __syncthreads();

    for (int t = 0; t < TT; ++t) {
        const u16* hc = hbuf[t & 1];
        u16* hn = hbuf[(t + 1) & 1];
        short8 bh[4];
#pragma unroll
        for (int kc = 0; kc < 4; ++kc)
            bh[kc] = *(const short8*)(hc + m * 136 + kc * 32 + q * 8);
        f4 aH[4];
#pragma unroll
        for (int g = 0; g < 4; ++g) aH[g] = (f4){0.f, 0.f, 0.f, 0.f};
#pragma unroll
        for (int kc = 0; kc < 4; ++kc)
#pragma unroll
            for (int g = 0; g < 4; ++g) aH[g] = MFMA(wh[g][kc], bh[kc], aH[g]);

        // prefetch xg(t+2) into regs (stays in flight across LDS barriers)
        int tp = (t + 2 < TT) ? (t + 2) : (TT - 1);
        u2 xnew = xg[(size_t)tp * 131072 + (size_t)blockIdx.x * 512 + tid];

        if (m < 4) {  // C col m = batch row; rows of C = units wv*16+4q+p
#pragma unroll
            for (int g = 0; g < 4; ++g)
#pragma unroll
                for (int p = 0; p < 4; ++p)
                    pre[m * 516 + (wv * 16 + 4 * q + p) * 4 + g] = aH[g][p];
        }
        lds_barrier();  // B1: pre visible

        f4 pv = *(const f4*)(pre + r * 516 + u * 4);
        float mm = dls[t * 4 + r];
        u32 w0 = xp0[0], w1 = xp0[1];
        float ip = __uint_as_float(w0 << 16)          + mm * pv[0];
        float fp = __uint_as_float(w0 & 0xFFFF0000u)  + mm * pv[1];
        float gp = __uint_as_float(w1 << 16)          + mm * pv[2];
        float op = __uint_as_float(w1 & 0xFFFF0000u)  + mm * pv[3];
        float ii = sig2(ip), ff = sig2(fp), gg = tanh2pre(gp), oo = sig2(op);
        float cc = ff * (mm * cst) + ii * gg;
        cst = cc;
        float hh = oo * tanh_c(cc);
        u16 hb = f2bf(hh);
        hn[r * 136 + u] = hb;
        hs[((size_t)t * BB + rb + r) * 128 + u] = hb;
        xp0 = xp1; xp1 = xnew;
        lds_barrier();  // B2: hn visible for next step's MFMA
    }
}

// ---------------- K4 (plain hs layout): heads ----------------
__global__ __launch_bounds__(256) void k4_heads_plain(
    const u16* __restrict__ hs, const u16* __restrict__ wf,
    const float* __restrict__ ba, const float* __restrict__ bc, float* __restrict__ out) {
    int tid = threadIdx.x, wv = tid >> 6, lane = tid & 63;
    int m = lane & 15, q = lane >> 4;
    int wid = blockIdx.x * 4 + wv;
    const short8* WAv = (const short8*)(wf + OFF_WA);
    short8 wab[2][4];
#pragma unroll
    for (int nt = 0; nt < 2; ++nt)
#pragma unroll
        for (int kc = 0; kc < 4; ++kc) wab[nt][kc] = WAv[(nt * 4 + kc) * 64 + lane];
    for (int it = 0; it < 8; ++it) {
        int c = wid + it * 2048;
        const u16* row = hs + ((size_t)c * 16 + m) * 128 + q * 8;
        short8 a[4];
#pragma unroll
        for (int kc = 0; kc < 4; ++kc) a[kc] = *(const short8*)(row + kc * 32);
#pragma unroll
        for (int nt = 0; nt < 2; ++nt) {
            f4 acc = {0.f, 0.f, 0.f, 0.f};
#pragma unroll
            for (int kc = 0; kc < 4; ++kc) acc = MFMA(a[kc], wab[nt][kc], acc);
            int col = nt * 16 + m;
            if (col < 19) {
                float bb = (col < 18) ? ba[col] : bc[0];
#pragma unroll
                for (int p = 0; p < 4; ++p)
                    out[(size_t)(c * 16 + q * 4 + p) * 19 + col] = acc[p] + bb;
            }
        }
    }
}

// ================= Fallback path (small ws): R1-style fused scan =================
__global__ __launch_bounds__(256) void k1_enc(
    const float* __restrict__ x, const float* __restrict__ b1, const float* __restrict__ b2,
    const float* __restrict__ b3, const u16* __restrict__ wf, u16* __restrict__ hid3f) {
    __shared__ __align__(16) u16 scr[4][2560];
    int tid = threadIdx.x, wv = tid >> 6, lane = tid & 63;
    int m = lane & 15, q = lane >> 4;
    u16* s1 = scr[wv];
    u16* s2 = scr[wv] + 2048;
    const short8* W1v = (const short8*)(wf + OFF_W1);
    const short8* W2v = (const short8*)(wf + OFF_W2);
    const short8* W3v = (const short8*)(wf + OFF_W3);
    int c = blockIdx.x * 4 + wv;
    short8 a1[4];
    const float* xr = x + (size_t)(c * 16 + m) * 128 + q * 8;
#pragma unroll
    for (int kc = 0; kc < 4; ++kc) {
        f4 f0 = *(const f4*)(xr + kc * 32);
        f4 f1 = *(const f4*)(xr + kc * 32 + 4);
        a1[kc] = pack8(f0, f1);
    }
#pragma unroll
    for (int nt = 0; nt < 8; ++nt) {
        f4 acc = {0.f, 0.f, 0.f, 0.f};
#pragma unroll
        for (int kc = 0; kc < 4; ++kc) acc = MFMA(a1[kc], W1v[(nt * 4 + kc) * 64 + lane], acc);
        int col = nt * 16 + m;
        float bb = b1[col];
        int base = (col >> 5) * 512 + ((col >> 3) & 3) * 128 + (col & 7);
#pragma unroll
        for (int p = 0; p < 4; ++p) {
            float v = acc[p] + bb; v = v > 0.f ? v : 0.f;
            s1[base + (q * 4 + p) * 8] = f2bf(v);
        }
    }
    short8 a2[4];
#pragma unroll
    for (int kc = 0; kc < 4; ++kc) a2[kc] = *(const short8*)(s1 + kc * 512 + lane * 8);
#pragma unroll
    for (int nt = 0; nt < 2; ++nt) {
        f4 acc = {0.f, 0.f, 0.f, 0.f};
#pragma unroll
        for (int kc = 0; kc < 4; ++kc) acc = MFMA(a2[kc], W2v[(nt * 4 + kc) * 64 + lane], acc);
        int col = nt * 16 + m;
        float bb = b2[col];
        int base = (col >> 3) * 128 + (col & 7);
#pragma unroll
        for (int p = 0; p < 4; ++p) {
            float v = acc[p] + bb; v = v > 0.f ? v : 0.f;
            s2[base + (q * 4 + p) * 8] = f2bf(v);
        }
    }
    short8 a3 = *(const short8*)(s2 + lane * 8);
#pragma unroll
    for (int nt = 0; nt < 8; ++nt) {
        f4 acc = {0.f, 0.f, 0.f, 0.f};
        acc = MFMA(a3, W3v[nt * 64 + lane], acc);
        int col = nt * 16 + m;
        float bb = b3[col];
        int base = (col >> 5) * 512 + ((col >> 3) & 3) * 128 + (col & 7);
#pragma unroll
        for (int p = 0; p < 4; ++p) {
            float v = acc[p] + bb; v = v > 0.f ? v : 0.f;
            s1[base + (q * 4 + p) * 8] = f2bf(v);
        }
    }
    u4* dst = (u4*)hid3f + (size_t)c * 256;
#pragma unroll
    for (int kc = 0; kc < 4; ++kc) dst[kc * 64 + lane] = *(const u4*)(s1 + kc * 512 + lane * 8);
}

__global__ __launch_bounds__(512) void k3_lstm(
    u16* __restrict__ hws, const u16* __restrict__ wf, const float* __restrict__ bih,
    const float* __restrict__ bhh, const float* __restrict__ done,
    const float* __restrict__ h0, const float* __restrict__ c0) {
    __shared__ __align__(16) u16 hbuf[2][2048];
    __shared__ __align__(16) float dls[4096];
    int tid = threadIdx.x, wv = tid >> 6, lane = tid & 63;
    int u15 = lane & 15, q = lane >> 4;
    int u = wv * 16 + u15;
    int rb = blockIdx.x * 16;
    const short8* WHv = (const short8*)(wf + OFF_WHH);
    const short8* WIv = (const short8*)(wf + OFF_WIH);
    short8 wh[4][4], wi[4][4];
#pragma unroll
    for (int g = 0; g < 4; ++g)
#pragma unroll
        for (int kc = 0; kc < 4; ++kc) {
            int nt = g * 8 + wv;
            wh[g][kc] = WHv[(nt * 4 + kc) * 64 + lane];
            wi[g][kc] = WIv[(nt * 4 + kc) * 64 + lane];
        }
    float bg[4];
#pragma unroll
    for (int g = 0; g < 4; ++g)
        bg[g] = (bih[g * 128 + u] + bhh[g * 128 + u]) * ((g == 2) ? SC2 : SC1);
    for (int i = tid; i < 4096; i += 512) {
        int t = i >> 4, r = i & 15;
        dls[i] = 1.0f - done[(size_t)t * BB + rb + r];
    }
    float cst[4];
#pragma unroll
    for (int k = 0; k < 4; ++k) {
        int r = 4 * q + k;
        cst[k] = c0[(size_t)(rb + r) * 128 + u];
        float hv = h0[(size_t)(rb + r) * 128 + u];
        hbuf[0][(u >> 5) * 512 + (((u >> 3) & 3) * 16 + r) * 8 + (u & 7)] = f2bf(hv);
    }
    const u4* h3 = (const u4*)hws;
    u4 xf[4];
#pragma unroll
    for (int kc = 0; kc < 4; ++kc) xf[kc] = h3[((size_t)blockIdx.x * 4 + kc) * 64 + lane];
    __syncthreads();
    for (int t = 0; t < TT; ++t) {
        const u16* hc = hbuf[t & 1];
        u16* hn = hbuf[(t + 1) & 1];
        short8 ah[4];
#pragma unroll
        for (int kc = 0; kc < 4; ++kc) ah[kc] = *(const short8*)(hc + kc * 512 + lane * 8);
        f4 aH[4], aX[4];
#pragma unroll
        for (int g = 0; g < 4; ++g) { aH[g] = (f4){0.f, 0.f, 0.f, 0.f}; aX[g] = (f4){0.f, 0.f, 0.f, 0.f}; }
#pragma unroll
        for (int kc = 0; kc < 4; ++kc) {
            short8 xs = u4_to_s8(xf[kc]);
#pragma unroll
            for (int g = 0; g < 4; ++g) {
                aH[g] = MFMA(ah[kc], wh[g][kc], aH[g]);
                aX[g] = MFMA(xs, wi[g][kc], aX[g]);
            }
        }
        if (t < TT - 1) {
#pragma unroll
            for (int kc = 0; kc < 4; ++kc)
                xf[kc] = h3[(((size_t)(t + 1) * 64 + blockIdx.x) * 4 + kc) * 64 + lane];
        }
        f4 dm = *(const f4*)(dls + t * 16 + 4 * q);
#pragma unroll
        for (int k = 0; k < 4; ++k) {
            float mm = dm[k];
            float ip = aX[0][k] + bg[0] + mm * aH[0][k];
            float fp = aX[1][k] + bg[1] + mm * aH[1][k];
            float gp = aX[2][k] + bg[2] + mm * aH[2][k];
            float op = aX[3][k] + bg[3] + mm * aH[3][k];
            float ii = sig2(ip), ff = sig2(fp), gg = tanh2pre(gp), oo = sig2(op);
            float cc = ff * (mm * cst[k]) + ii * gg;
            cst[k] = cc;
            float hh = oo * tanh_c(cc);
            hn[(u >> 5) * 512 + (((u >> 3) & 3) * 16 + (4 * q + k)) * 8 + (u & 7)] = f2bf(hh);
        }
        lds_barrier();
        if (wv < 4) {
            u4 v = *(const u4*)(hn + wv * 512 + lane * 8);
            ((u4*)hws)[(((size_t)t * 64 + blockIdx.x) * 4 + wv) * 64 + lane] = v;
        }
    }
}

__global__ __launch_bounds__(256) void k4_heads_frag(
    const u16* __restrict__ hsf, const u16* __restrict__ wf,
    const float* __restrict__ ba, const float* __restrict__ bc, float* __restrict__ out) {
    int tid = threadIdx.x, wv = tid >> 6, lane = tid & 63;
    int m = lane & 15, q = lane >> 4;
    int wid = blockIdx.x * 4 + wv;
    const short8* WAv = (const short8*)(wf + OFF_WA);
    short8 wab[2][4];
#pragma unroll
    for (int nt = 0; nt < 2; ++nt)
#pragma unroll
        for (int kc = 0; kc < 4; ++kc) wab[nt][kc] = WAv[(nt * 4 + kc) * 64 + lane];
    const short8* A = (const short8*)hsf;
    for (int it = 0; it < 8; ++it) {
        int c = wid + it * 2048;
        short8 a[4];
#pragma unroll
        for (int kc = 0; kc < 4; ++kc) a[kc] = A[((size_t)c * 4 + kc) * 64 + lane];
#pragma unroll
        for (int nt = 0; nt < 2; ++nt) {
            f4 acc = {0.f, 0.f, 0.f, 0.f};
#pragma unroll
            for (int kc = 0; kc < 4; ++kc) acc = MFMA(a[kc], wab[nt][kc], acc);
            int col = nt * 16 + m;
            if (col < 19) {
                float bb = (col < 18) ? ba[col] : bc[0];
#pragma unroll
                for (int p = 0; p < 4; ++p)
                    out[(size_t)(c * 16 + q * 4 + p) * 19 + col] = acc[p] + bb;
            }
        }
    }
}

extern "C" void kernel_launch(void* const* d_in, const int* in_sizes, int n_in,
                              void* d_out, int out_size, void* d_ws, size_t ws_size,
                              hipStream_t stream) {
    const float* x    = (const float*)d_in[0];
    const float* done = (const float*)d_in[1];
    const float* h0   = (const float*)d_in[2];
    const float* c0   = (const float*)d_in[3];
    const float* W1   = (const float*)d_in[4];
    const float* b1   = (const float*)d_in[5];
    const float* W2   = (const float*)d_in[6];
    const float* b2   = (const float*)d_in[7];
    const float* W3   = (const float*)d_in[8];
    const float* b3   = (const float*)d_in[9];
    const float* Wih  = (const float*)d_in[10];
    const float* Whh  = (const float*)d_in[11];
    const float* bih  = (const float*)d_in[12];
    const float* bhh  = (const float*)d_in[13];
    const float* Wa   = (const float*)d_in[14];
    const float* ba   = (const float*)d_in[15];
    const float* Wc   = (const float*)d_in[16];
    const float* bc   = (const float*)d_in[17];
    float* out = (float*)d_out;
    u16* ws = (u16*)d_ws;

    if (ws_size >= WS_NEED_BIG) {
        u2*  xg = (u2*)ws;
        u16* hs = ws + WS_HS_OFF;
        u16* wf = ws + WS_WF_OFF;
        hipLaunchKernelGGL(k0_conv, dim3(128), dim3(256), 0, stream,
                           W1, W2, W3, Wih, Whh, Wa, Wc, wf);
        hipLaunchKernelGGL(k1_fused, dim3(4096), dim3(256), 0, stream,
                           x, b1, b2, b3, bih, bhh, wf, xg);
        hipLaunchKernelGGL(k3_scan, dim3(256), dim3(512), 0, stream,
                           xg, hs, wf, done, h0, c0);
        hipLaunchKernelGGL(k4_heads_plain, dim3(512), dim3(256), 0, stream,
                           hs, wf, ba, bc, out);
    } else {
        u16* hid3f = ws;
        u16* wf    = ws + (size_t)NN * 128;
        hipLaunchKernelGGL(k0_conv, dim3(128), dim3(256), 0, stream,
                           W1, W2, W3, Wih, Whh, Wa, Wc, wf);
        hipLaunchKernelGGL(k1_enc, dim3(4096), dim3(256), 0, stream,
                           x, b1, b2, b3, wf, hid3f);
        hipLaunchKernelGGL(k3_lstm, dim3(64), dim3(512), 0, stream,
                           hid3f, wf, bih, bhh, done, h0, c0);
        hipLaunchKernelGGL(k4_heads_frag, dim3(512), dim3(256), 0, stream,
                           hid3f, wf, ba, bc, out);
    }
}

// Round 4
// 592.258 us; speedup vs baseline: 1.2109x; 1.0110x over previous
//
#include <hip/hip_runtime.h>
#include <hip/hip_bf16.h>

typedef unsigned short u16;
typedef unsigned int u32;
typedef __attribute__((ext_vector_type(8))) short short8;
typedef __attribute__((ext_vector_type(4))) float f4;
typedef __attribute__((ext_vector_type(4))) u32 u4;
typedef __attribute__((ext_vector_type(2))) u32 u2;

#define MFMA(a, b, c) __builtin_amdgcn_mfma_f32_16x16x32_bf16((a), (b), (c), 0, 0, 0)

// ---- constants ----
#define TT 256
#define BB 1024
#define NN (TT * BB)          // 262144 rows
#define SC1 1.4426950408889634f   // log2(e), folded into i,f,o gate rows
#define SC2 2.8853900817779268f   // 2*log2(e), folded into g gate rows

// wf internal offsets (u16 units)
#define OFF_W1  0
#define OFF_W2  16384
#define OFF_W3  20480
#define OFF_WIH 24576
#define OFF_WHH 90112
#define OFF_WA  155648
#define WF_TOT  159744

// big-path ws layout (u16 units): xg[NN*128 u2 = 134217728 u16] | hs[33554432] | wf[159744]
#define WS_HS_OFF 134217728
#define WS_WF_OFF 167772160
#define WS_NEED_BIG 335863808ULL
// fallback layout: hid3f[33554432] | wf[159744]

static __device__ __forceinline__ u16 f2bf(float f) {
    u32 u = __float_as_uint(f);
    u32 r = (u + 0x7FFFu + ((u >> 16) & 1u)) >> 16;
    return (u16)r;
}
static __device__ __forceinline__ short8 pack8(f4 a, f4 b) {
    short8 r;
    r[0] = (short)f2bf(a[0]); r[1] = (short)f2bf(a[1]);
    r[2] = (short)f2bf(a[2]); r[3] = (short)f2bf(a[3]);
    r[4] = (short)f2bf(b[0]); r[5] = (short)f2bf(b[1]);
    r[6] = (short)f2bf(b[2]); r[7] = (short)f2bf(b[3]);
    return r;
}
static __device__ __forceinline__ short8 u4_to_s8(u4 v) {
    union { u4 u; short8 s; } t; t.u = v; return t.s;
}
// x already scaled by log2e (folded into weights/bias)
static __device__ __forceinline__ float sig2(float x) {
    return __builtin_amdgcn_rcpf(1.f + __builtin_amdgcn_exp2f(-x));
}
// x already scaled by 2*log2e
static __device__ __forceinline__ float tanh2pre(float x) {
    return 2.f * __builtin_amdgcn_rcpf(1.f + __builtin_amdgcn_exp2f(-x)) - 1.f;
}
// unscaled argument (cell state)
static __device__ __forceinline__ float tanh_c(float x) {
    return 2.f * __builtin_amdgcn_rcpf(1.f + __builtin_amdgcn_exp2f(-SC2 * x)) - 1.f;
}
// LDS-only barrier: no vmcnt drain; global stores / prefetch loads stay in flight.
static __device__ __forceinline__ void lds_barrier() {
    asm volatile("s_waitcnt lgkmcnt(0)\n\ts_barrier" ::: "memory");
}

// ---------------- K0: weights fp32 -> bf16 fragment order (gate rows pre-scaled) ----------------
static __device__ void convW128(const float* src, int Nn, u16* dst, int tid, int nth) {
    int tot = Nn * 128;
    for (int d = tid; d < tot; d += nth) {
        int j = d & 7, l = (d >> 3) & 63, ck = d >> 9;
        int kc = ck & 3, nt = ck >> 2;
        int n = nt * 16 + (l & 15), k = kc * 32 + ((l >> 4) << 3) + j;
        dst[d] = f2bf(src[n * 128 + k]);
    }
}
static __device__ void convW128s(const float* src, u16* dst, int tid, int nth) {
    // 512 x 128, rows scaled per gate: i,f,o -> SC1 ; g -> SC2
    int tot = 512 * 128;
    for (int d = tid; d < tot; d += nth) {
        int j = d & 7, l = (d >> 3) & 63, ck = d >> 9;
        int kc = ck & 3, nt = ck >> 2;
        int n = nt * 16 + (l & 15), k = kc * 32 + ((l >> 4) << 3) + j;
        float s = ((n >> 7) == 2) ? SC2 : SC1;
        dst[d] = f2bf(src[n * 128 + k] * s);
    }
}
static __device__ void convW32(const float* src, int Nn, u16* dst, int tid, int nth) {
    int tot = Nn * 32;
    for (int d = tid; d < tot; d += nth) {
        int j = d & 7, l = (d >> 3) & 63, nt = d >> 9;
        int n = nt * 16 + (l & 15), k = ((l >> 4) << 3) + j;
        dst[d] = f2bf(src[n * 32 + k]);
    }
}

__global__ void k0_conv(const float* __restrict__ W1, const float* __restrict__ W2,
                        const float* __restrict__ W3, const float* __restrict__ Wih,
                        const float* __restrict__ Whh, const float* __restrict__ Wa,
                        const float* __restrict__ Wc, u16* __restrict__ wf) {
    int tid = blockIdx.x * blockDim.x + threadIdx.x;
    int nth = gridDim.x * blockDim.x;
    convW128(W1, 128, wf + OFF_W1, tid, nth);
    convW128(W2, 32, wf + OFF_W2, tid, nth);
    convW32(W3, 128, wf + OFF_W3, tid, nth);
    convW128s(Wih, wf + OFF_WIH, tid, nth);
    convW128s(Whh, wf + OFF_WHH, tid, nth);
    for (int d = tid; d < 32 * 128; d += nth) {
        int j = d & 7, l = (d >> 3) & 63, ck = d >> 9;
        int kc = ck & 3, nt = ck >> 2;
        int n = nt * 16 + (l & 15), k = kc * 32 + ((l >> 4) << 3) + j;
        float v = (n < 18) ? Wa[n * 128 + k] : ((n == 18) ? Wc[k] : 0.f);
        wf[OFF_WA + d] = f2bf(v);
    }
}

// ---------------- K1-fused: encoder (3 layers) + xg = hid3 @ Wih^T + bias ----------------
// xg layout (row-major): u2[row*128 + unit] = 4 packed bf16 gate pre-acts (i,f | g,o).
__global__ __launch_bounds__(256) void k1_fused(
    const float* __restrict__ x, const float* __restrict__ b1, const float* __restrict__ b2,
    const float* __restrict__ b3, const float* __restrict__ bih, const float* __restrict__ bhh,
    const u16* __restrict__ wf, u2* __restrict__ xg) {
    __shared__ __align__(16) u16 scr[4][2560];
    __shared__ float biasL[512];

    int tid = threadIdx.x, wv = tid >> 6, lane = tid & 63;
    int m = lane & 15, q = lane >> 4;
    u16* s1 = scr[wv];
    u16* s2 = scr[wv] + 2048;
    const short8* W1v = (const short8*)(wf + OFF_W1);
    const short8* W2v = (const short8*)(wf + OFF_W2);
    const short8* W3v = (const short8*)(wf + OFF_W3);
    const short8* WIv = (const short8*)(wf + OFF_WIH);
    int c = blockIdx.x * 4 + wv;  // chunk id [0,16384)

    for (int i = tid; i < 512; i += 256)
        biasL[i] = (bih[i] + bhh[i]) * (((i >> 7) == 2) ? SC2 : SC1);

    short8 a1[4];
    const float* xr = x + (size_t)(c * 16 + m) * 128 + q * 8;
#pragma unroll
    for (int kc = 0; kc < 4; ++kc) {
        f4 f0 = *(const f4*)(xr + kc * 32);
        f4 f1 = *(const f4*)(xr + kc * 32 + 4);
        a1[kc] = pack8(f0, f1);
    }
    // Layer 1: 128 -> 128
#pragma unroll
    for (int nt = 0; nt < 8; ++nt) {
        f4 acc = {0.f, 0.f, 0.f, 0.f};
#pragma unroll
        for (int kc = 0; kc < 4; ++kc) acc = MFMA(a1[kc], W1v[(nt * 4 + kc) * 64 + lane], acc);
        int col = nt * 16 + m;
        float bb = b1[col];
        int base = (col >> 5) * 512 + ((col >> 3) & 3) * 128 + (col & 7);
#pragma unroll
        for (int p = 0; p < 4; ++p) {
            float v = acc[p] + bb; v = v > 0.f ? v : 0.f;
            s1[base + (q * 4 + p) * 8] = f2bf(v);
        }
    }
    short8 a2[4];
#pragma unroll
    for (int kc = 0; kc < 4; ++kc) a2[kc] = *(const short8*)(s1 + kc * 512 + lane * 8);
    // Layer 2: 128 -> 32
#pragma unroll
    for (int nt = 0; nt < 2; ++nt) {
        f4 acc = {0.f, 0.f, 0.f, 0.f};
#pragma unroll
        for (int kc = 0; kc < 4; ++kc) acc = MFMA(a2[kc], W2v[(nt * 4 + kc) * 64 + lane], acc);
        int col = nt * 16 + m;
        float bb = b2[col];
        int base = (col >> 3) * 128 + (col & 7);
#pragma unroll
        for (int p = 0; p < 4; ++p) {
            float v = acc[p] + bb; v = v > 0.f ? v : 0.f;
            s2[base + (q * 4 + p) * 8] = f2bf(v);
        }
    }
    short8 a3 = *(const short8*)(s2 + lane * 8);
    // Layer 3: 32 -> 128 (hid3 stays in s1, frag order)
#pragma unroll
    for (int nt = 0; nt < 8; ++nt) {
        f4 acc = {0.f, 0.f, 0.f, 0.f};
        acc = MFMA(a3, W3v[nt * 64 + lane], acc);
        int col = nt * 16 + m;
        float bb = b3[col];
        int base = (col >> 5) * 512 + ((col >> 3) & 3) * 128 + (col & 7);
#pragma unroll
        for (int p = 0; p < 4; ++p) {
            float v = acc[p] + bb; v = v > 0.f ? v : 0.f;
            s1[base + (q * 4 + p) * 8] = f2bf(v);
        }
    }
    __syncthreads();  // biasL visibility (once)

    // xg GEMM in row-layout: A = hid3 rows (from s1), B = Wih frags.
    // C: rows = batch rows (4q+p), cols = units uw*16+m  -> coalesced u2 stores.
    short8 afr[4];
#pragma unroll
    for (int kc = 0; kc < 4; ++kc) afr[kc] = *(const short8*)(s1 + kc * 512 + lane * 8);
#pragma unroll
    for (int uw = 0; uw < 8; ++uw) {
        f4 acc[4];
#pragma unroll
        for (int g = 0; g < 4; ++g) acc[g] = (f4){0.f, 0.f, 0.f, 0.f};
#pragma unroll
        for (int kc = 0; kc < 4; ++kc)
#pragma unroll
            for (int g = 0; g < 4; ++g)
                acc[g] = MFMA(afr[kc], WIv[(((g * 8 + uw) * 4) + kc) * 64 + lane], acc[g]);
        float bs0 = biasL[uw * 16 + m];
        float bs1 = biasL[128 + uw * 16 + m];
        float bs2 = biasL[256 + uw * 16 + m];
        float bs3 = biasL[384 + uw * 16 + m];
#pragma unroll
        for (int p = 0; p < 4; ++p) {
            size_t row = (size_t)c * 16 + 4 * q + p;
            u2 pk;
            pk[0] = ((u32)f2bf(acc[1][p] + bs1) << 16) | (u32)f2bf(acc[0][p] + bs0);
            pk[1] = ((u32)f2bf(acc[3][p] + bs3) << 16) | (u32)f2bf(acc[2][p] + bs2);
            xg[row * 128 + uw * 16 + m] = pk;
        }
    }
}

// ---------------- K3: LSTM scan, 256 blocks x 4 rows x 512 threads ----------------
// Transposed gates MFMA (A=Whh regs, B=h-frag LDS); pre-acts via conflict-free pre2 LDS;
// xg row-major, even/odd register prefetch (distance 2, no register rotation).
__global__ __launch_bounds__(512) void k3_scan(
    const u2* __restrict__ xg, u16* __restrict__ hs, const u16* __restrict__ wf,
    const float* __restrict__ done, const float* __restrict__ h0, const float* __restrict__ c0) {
    __shared__ __align__(16) u16 hbuf[2][16 * 136];  // rows 0-3 live, 4-15 zero
    __shared__ __align__(16) float pre2[16 * 132];   // [(g*4+row)*132 + unit]
    __shared__ float dls[1024];                      // (1-done)[t*4+r]

    int tid = threadIdx.x, wv = tid >> 6, lane = tid & 63;
    int m = lane & 15, q = lane >> 4;
    int rb = blockIdx.x * 4;
    const short8* WHv = (const short8*)(wf + OFF_WHH);

    short8 wh[4][4];  // A-frags: gate g, unit-group wv
#pragma unroll
    for (int g = 0; g < 4; ++g)
#pragma unroll
        for (int kc = 0; kc < 4; ++kc)
            wh[g][kc] = WHv[(((g * 8 + wv) * 4) + kc) * 64 + lane];

    // zero hbuf rows 4..15 of both buffers
    for (int i = tid; i < 2 * 12 * 136; i += 512) {
        int b = i / 1632, rem = i % 1632;
        hbuf[b][(4 + rem / 136) * 136 + (rem % 136)] = 0;
    }
    for (int i = tid; i < 1024; i += 512)
        dls[i] = 1.0f - done[(size_t)(i >> 2) * BB + rb + (i & 3)];

    int r = tid >> 7, u = tid & 127;     // this thread's cell
    float cst = c0[(size_t)(rb + r) * 128 + u];
    hbuf[0][r * 136 + u] = f2bf(h0[(size_t)(rb + r) * 128 + u]);

    size_t xbase = (size_t)(rb + r) * 128 + u;  // + t*BB*128 per step
    u2 xA = xg[xbase];                 // t=0
    u2 xB = xg[xbase + (size_t)BB * 128];  // t=1
    __syncthreads();

    auto step = [&](int t, const u16* hc, u16* hn, u2& X) {
        short8 bh[4];
#pragma unroll
        for (int kc = 0; kc < 4; ++kc)
            bh[kc] = *(const short8*)(hc + m * 136 + kc * 32 + q * 8);
        f4 aH[4];
#pragma unroll
        for (int g = 0; g < 4; ++g) aH[g] = (f4){0.f, 0.f, 0.f, 0.f};
#pragma unroll
        for (int kc = 0; kc < 4; ++kc)
#pragma unroll
            for (int g = 0; g < 4; ++g) aH[g] = MFMA(wh[g][kc], bh[kc], aH[g]);

        if (m < 4) {
#pragma unroll
            for (int g = 0; g < 4; ++g)
                *(f4*)(pre2 + (g * 4 + m) * 132 + wv * 16 + 4 * q) = aH[g];
        }
        lds_barrier();  // B1: pre2 visible

        // consume X, then immediately re-load it for t+2 (wait lands 2 steps out)
        u32 w0 = X[0], w1 = X[1];
        int tn = (t + 2 < TT) ? (t + 2) : (TT - 1);
        X = xg[xbase + (size_t)tn * (BB * 128)];

        float mm = dls[t * 4 + r];
        float p0 = pre2[(0 * 4 + r) * 132 + u];
        float p1 = pre2[(1 * 4 + r) * 132 + u];
        float p2 = pre2[(2 * 4 + r) * 132 + u];
        float p3 = pre2[(3 * 4 + r) * 132 + u];
        float ip = __uint_as_float(w0 << 16)         + mm * p0;
        float fp = __uint_as_float(w0 & 0xFFFF0000u) + mm * p1;
        float gp = __uint_as_float(w1 << 16)         + mm * p2;
        float op = __uint_as_float(w1 & 0xFFFF0000u) + mm * p3;
        float ii = sig2(ip), ff = sig2(fp), gg = tanh2pre(gp), oo = sig2(op);
        float cc = ff * (mm * cst) + ii * gg;
        cst = cc;
        float hh = oo * tanh_c(cc);
        u16 hb = f2bf(hh);
        hn[r * 136 + u] = hb;
        hs[((size_t)t * BB + rb + r) * 128 + u] = hb;
        lds_barrier();  // B2: hn visible for next step
    };

    for (int t = 0; t < TT; t += 2) {
        step(t,     hbuf[0], hbuf[1], xA);
        step(t + 1, hbuf[1], hbuf[0], xB);
    }
}

// ---------------- K4 (plain hs layout): heads ----------------
__global__ __launch_bounds__(256) void k4_heads_plain(
    const u16* __restrict__ hs, const u16* __restrict__ wf,
    const float* __restrict__ ba, const float* __restrict__ bc, float* __restrict__ out) {
    int tid = threadIdx.x, wv = tid >> 6, lane = tid & 63;
    int m = lane & 15, q = lane >> 4;
    int wid = blockIdx.x * 4 + wv;
    const short8* WAv = (const short8*)(wf + OFF_WA);
    short8 wab[2][4];
#pragma unroll
    for (int nt = 0; nt < 2; ++nt)
#pragma unroll
        for (int kc = 0; kc < 4; ++kc) wab[nt][kc] = WAv[(nt * 4 + kc) * 64 + lane];
    for (int it = 0; it < 8; ++it) {
        int c = wid + it * 2048;
        const u16* row = hs + ((size_t)c * 16 + m) * 128 + q * 8;
        short8 a[4];
#pragma unroll
        for (int kc = 0; kc < 4; ++kc) a[kc] = *(const short8*)(row + kc * 32);
#pragma unroll
        for (int nt = 0; nt < 2; ++nt) {
            f4 acc = {0.f, 0.f, 0.f, 0.f};
#pragma unroll
            for (int kc = 0; kc < 4; ++kc) acc = MFMA(a[kc], wab[nt][kc], acc);
            int col = nt * 16 + m;
            if (col < 19) {
                float bb = (col < 18) ? ba[col] : bc[0];
#pragma unroll
                for (int p = 0; p < 4; ++p)
                    out[(size_t)(c * 16 + q * 4 + p) * 19 + col] = acc[p] + bb;
            }
        }
    }
}

// ================= Fallback path (small ws): R1-style fused scan =================
__global__ __launch_bounds__(256) void k1_enc(
    const float* __restrict__ x, const float* __restrict__ b1, const float* __restrict__ b2,
    const float* __restrict__ b3, const u16* __restrict__ wf, u16* __restrict__ hid3f) {
    __shared__ __align__(16) u16 scr[4][2560];
    int tid = threadIdx.x, wv = tid >> 6, lane = tid & 63;
    int m = lane & 15, q = lane >> 4;
    u16* s1 = scr[wv];
    u16* s2 = scr[wv] + 2048;
    const short8* W1v = (const short8*)(wf + OFF_W1);
    const short8* W2v = (const short8*)(wf + OFF_W2);
    const short8* W3v = (const short8*)(wf + OFF_W3);
    int c = blockIdx.x * 4 + wv;
    short8 a1[4];
    const float* xr = x + (size_t)(c * 16 + m) * 128 + q * 8;
#pragma unroll
    for (int kc = 0; kc < 4; ++kc) {
        f4 f0 = *(const f4*)(xr + kc * 32);
        f4 f1 = *(const f4*)(xr + kc * 32 + 4);
        a1[kc] = pack8(f0, f1);
    }
#pragma unroll
    for (int nt = 0; nt < 8; ++nt) {
        f4 acc = {0.f, 0.f, 0.f, 0.f};
#pragma unroll
        for (int kc = 0; kc < 4; ++kc) acc = MFMA(a1[kc], W1v[(nt * 4 + kc) * 64 + lane], acc);
        int col = nt * 16 + m;
        float bb = b1[col];
        int base = (col >> 5) * 512 + ((col >> 3) & 3) * 128 + (col & 7);
#pragma unroll
        for (int p = 0; p < 4; ++p) {
            float v = acc[p] + bb; v = v > 0.f ? v : 0.f;
            s1[base + (q * 4 + p) * 8] = f2bf(v);
        }
    }
    short8 a2[4];
#pragma unroll
    for (int kc = 0; kc < 4; ++kc) a2[kc] = *(const short8*)(s1 + kc * 512 + lane * 8);
#pragma unroll
    for (int nt = 0; nt < 2; ++nt) {
        f4 acc = {0.f, 0.f, 0.f, 0.f};
#pragma unroll
        for (int kc = 0; kc < 4; ++kc) acc = MFMA(a2[kc], W2v[(nt * 4 + kc) * 64 + lane], acc);
        int col = nt * 16 + m;
        float bb = b2[col];
        int base = (col >> 3) * 128 + (col & 7);
#pragma unroll
        for (int p = 0; p < 4; ++p) {
            float v = acc[p] + bb; v = v > 0.f ? v : 0.f;
            s2[base + (q * 4 + p) * 8] = f2bf(v);
        }
    }
    short8 a3 = *(const short8*)(s2 + lane * 8);
#pragma unroll
    for (int nt = 0; nt < 8; ++nt) {
        f4 acc = {0.f, 0.f, 0.f, 0.f};
        acc = MFMA(a3, W3v[nt * 64 + lane], acc);
        int col = nt * 16 + m;
        float bb = b3[col];
        int base = (col >> 5) * 512 + ((col >> 3) & 3) * 128 + (col & 7);
#pragma unroll
        for (int p = 0; p < 4; ++p) {
            float v = acc[p] + bb; v = v > 0.f ? v : 0.f;
            s1[base + (q * 4 + p) * 8] = f2bf(v);
        }
    }
    u4* dst = (u4*)hid3f + (size_t)c * 256;
#pragma unroll
    for (int kc = 0; kc < 4; ++kc) dst[kc * 64 + lane] = *(const u4*)(s1 + kc * 512 + lane * 8);
}

__global__ __launch_bounds__(512) void k3_lstm(
    u16* __restrict__ hws, const u16* __restrict__ wf, const float* __restrict__ bih,
    const float* __restrict__ bhh, const float* __restrict__ done,
    const float* __restrict__ h0, const float* __restrict__ c0) {
    __shared__ __align__(16) u16 hbuf[2][2048];
    __shared__ __align__(16) float dls[4096];
    int tid = threadIdx.x, wv = tid >> 6, lane = tid & 63;
    int u15 = lane & 15, q = lane >> 4;
    int u = wv * 16 + u15;
    int rb = blockIdx.x * 16;
    const short8* WHv = (const short8*)(wf + OFF_WHH);
    const short8* WIv = (const short8*)(wf + OFF_WIH);
    short8 wh[4][4], wi[4][4];
#pragma unroll
    for (int g = 0; g < 4; ++g)
#pragma unroll
        for (int kc = 0; kc < 4; ++kc) {
            int nt = g * 8 + wv;
            wh[g][kc] = WHv[(nt * 4 + kc) * 64 + lane];
            wi[g][kc] = WIv[(nt * 4 + kc) * 64 + lane];
        }
    float bg[4];
#pragma unroll
    for (int g = 0; g < 4; ++g)
        bg[g] = (bih[g * 128 + u] + bhh[g * 128 + u]) * ((g == 2) ? SC2 : SC1);
    for (int i = tid; i < 4096; i += 512) {
        int t = i >> 4, r = i & 15;
        dls[i] = 1.0f - done[(size_t)t * BB + rb + r];
    }
    float cst[4];
#pragma unroll
    for (int k = 0; k < 4; ++k) {
        int r = 4 * q + k;
        cst[k] = c0[(size_t)(rb + r) * 128 + u];
        float hv = h0[(size_t)(rb + r) * 128 + u];
        hbuf[0][(u >> 5) * 512 + (((u >> 3) & 3) * 16 + r) * 8 + (u & 7)] = f2bf(hv);
    }
    const u4* h3 = (const u4*)hws;
    u4 xf[4];
#pragma unroll
    for (int kc = 0; kc < 4; ++kc) xf[kc] = h3[((size_t)blockIdx.x * 4 + kc) * 64 + lane];
    __syncthreads();
    for (int t = 0; t < TT; ++t) {
        const u16* hc = hbuf[t & 1];
        u16* hn = hbuf[(t + 1) & 1];
        short8 ah[4];
#pragma unroll
        for (int kc = 0; kc < 4; ++kc) ah[kc] = *(const short8*)(hc + kc * 512 + lane * 8);
        f4 aH[4], aX[4];
#pragma unroll
        for (int g = 0; g < 4; ++g) { aH[g] = (f4){0.f, 0.f, 0.f, 0.f}; aX[g] = (f4){0.f, 0.f, 0.f, 0.f}; }
#pragma unroll
        for (int kc = 0; kc < 4; ++kc) {
            short8 xs = u4_to_s8(xf[kc]);
#pragma unroll
            for (int g = 0; g < 4; ++g) {
                aH[g] = MFMA(ah[kc], wh[g][kc], aH[g]);
                aX[g] = MFMA(xs, wi[g][kc], aX[g]);
            }
        }
        if (t < TT - 1) {
#pragma unroll
            for (int kc = 0; kc < 4; ++kc)
                xf[kc] = h3[(((size_t)(t + 1) * 64 + blockIdx.x) * 4 + kc) * 64 + lane];
        }
        f4 dm = *(const f4*)(dls + t * 16 + 4 * q);
#pragma unroll
        for (int k = 0; k < 4; ++k) {
            float mm = dm[k];
            float ip = aX[0][k] + bg[0] + mm * aH[0][k];
            float fp = aX[1][k] + bg[1] + mm * aH[1][k];
            float gp = aX[2][k] + bg[2] + mm * aH[2][k];
            float op = aX[3][k] + bg[3] + mm * aH[3][k];
            float ii = sig2(ip), ff = sig2(fp), gg = tanh2pre(gp), oo = sig2(op);
            float cc = ff * (mm * cst[k]) + ii * gg;
            cst[k] = cc;
            float hh = oo * tanh_c(cc);
            hn[(u >> 5) * 512 + (((u >> 3) & 3) * 16 + (4 * q + k)) * 8 + (u & 7)] = f2bf(hh);
        }
        lds_barrier();
        if (wv < 4) {
            u4 v = *(const u4*)(hn + wv * 512 + lane * 8);
            ((u4*)hws)[(((size_t)t * 64 + blockIdx.x) * 4 + wv) * 64 + lane] = v;
        }
    }
}

__global__ __launch_bounds__(256) void k4_heads_frag(
    const u16* __restrict__ hsf, const u16* __restrict__ wf,
    const float* __restrict__ ba, const float* __restrict__ bc, float* __restrict__ out) {
    int tid = threadIdx.x, wv = tid >> 6, lane = tid & 63;
    int m = lane & 15, q = lane >> 4;
    int wid = blockIdx.x * 4 + wv;
    const short8* WAv = (const short8*)(wf + OFF_WA);
    short8 wab[2][4];
#pragma unroll
    for (int nt = 0; nt < 2; ++nt)
#pragma unroll
        for (int kc = 0; kc < 4; ++kc) wab[nt][kc] = WAv[(nt * 4 + kc) * 64 + lane];
    const short8* A = (const short8*)hsf;
    for (int it = 0; it < 8; ++it) {
        int c = wid + it * 2048;
        short8 a[4];
#pragma unroll
        for (int kc = 0; kc < 4; ++kc) a[kc] = A[((size_t)c * 4 + kc) * 64 + lane];
#pragma unroll
        for (int nt = 0; nt < 2; ++nt) {
            f4 acc = {0.f, 0.f, 0.f, 0.f};
#pragma unroll
            for (int kc = 0; kc < 4; ++kc) acc = MFMA(a[kc], wab[nt][kc], acc);
            int col = nt * 16 + m;
            if (col < 19) {
                float bb = (col < 18) ? ba[col] : bc[0];
#pragma unroll
                for (int p = 0; p < 4; ++p)
                    out[(size_t)(c * 16 + q * 4 + p) * 19 + col] = acc[p] + bb;
            }
        }
    }
}

extern "C" void kernel_launch(void* const* d_in, const int* in_sizes, int n_in,
                              void* d_out, int out_size, void* d_ws, size_t ws_size,
                              hipStream_t stream) {
    const float* x    = (const float*)d_in[0];
    const float* done = (const float*)d_in[1];
    const float* h0   = (const float*)d_in[2];
    const float* c0   = (const float*)d_in[3];
    const float* W1   = (const float*)d_in[4];
    const float* b1   = (const float*)d_in[5];
    const float* W2   = (const float*)d_in[6];
    const float* b2   = (const float*)d_in[7];
    const float* W3   = (const float*)d_in[8];
    const float* b3   = (const float*)d_in[9];
    const float* Wih  = (const float*)d_in[10];
    const float* Whh  = (const float*)d_in[11];
    const float* bih  = (const float*)d_in[12];
    const float* bhh  = (const float*)d_in[13];
    const float* Wa   = (const float*)d_in[14];
    const float* ba   = (const float*)d_in[15];
    const float* Wc   = (const float*)d_in[16];
    const float* bc   = (const float*)d_in[17];
    float* out = (float*)d_out;
    u16* ws = (u16*)d_ws;

    if (ws_size >= WS_NEED_BIG) {
        u2*  xg = (u2*)ws;
        u16* hs = ws + WS_HS_OFF;
        u16* wf = ws + WS_WF_OFF;
        hipLaunchKernelGGL(k0_conv, dim3(128), dim3(256), 0, stream,
                           W1, W2, W3, Wih, Whh, Wa, Wc, wf);
        hipLaunchKernelGGL(k1_fused, dim3(4096), dim3(256), 0, stream,
                           x, b1, b2, b3, bih, bhh, wf, xg);
        hipLaunchKernelGGL(k3_scan, dim3(256), dim3(512), 0, stream,
                           xg, hs, wf, done, h0, c0);
        hipLaunchKernelGGL(k4_heads_plain, dim3(512), dim3(256), 0, stream,
                           hs, wf, ba, bc, out);
    } else {
        u16* hid3f = ws;
        u16* wf    = ws + (size_t)NN * 128;
        hipLaunchKernelGGL(k0_conv, dim3(128), dim3(256), 0, stream,
                           W1, W2, W3, Wih, Whh, Wa, Wc, wf);
        hipLaunchKernelGGL(k1_enc, dim3(4096), dim3(256), 0, stream,
                           x, b1, b2, b3, wf, hid3f);
        hipLaunchKernelGGL(k3_lstm, dim3(64), dim3(512), 0, stream,
                           hid3f, wf, bih, bhh, done, h0, c0);
        hipLaunchKernelGGL(k4_heads_frag, dim3(512), dim3(256), 0, stream,
                           hid3f, wf, ba, bc, out);
    }
}